// Round 5
// baseline (224.042 us; speedup 1.0000x reference)
//
#include <hip/hip_runtime.h>
#include <hip/hip_bf16.h>
#include <math.h>

#define D_MODEL 32
#define S_LEN   2048
#define B_SZ    8
#define NTOK    (B_SZ * S_LEN)
#define LN_EPS  1e-5f
#define LOG2E   1.44269504088896340736f
#define QK_SCALE 0.35355339059327373f   /* 1/sqrt(8) */
#define MASKV   (-1.0e9f)               /* exp2(-1e9) == 0 */
#define CK      8                        /* keys per DMA chunk */

typedef const __attribute__((address_space(1))) void* gp_t;
typedef __attribute__((address_space(3))) void* sp_t;

__device__ __forceinline__ void dma16(const void* g, void* s) {
    __builtin_amdgcn_global_load_lds((gp_t)g, (sp_t)s, 16, 0, 0);
}

// ---------------------------------------------------------------------------
__global__ void detect_mask_dtype(const unsigned char* __restrict__ mb,
                                  int* __restrict__ flag) {
    int t = threadIdx.x;  // 64 lanes
    unsigned char b1 = mb[t * 4 + 1];
    unsigned char b2 = mb[t * 4 + 2];
    unsigned char b3 = mb[t * 4 + 3];
    int ok = ((b1 | b2 | b3) == 0);
    unsigned long long vote = __ballot(ok);
    if (t == 0) flag[0] = (vote == ~0ULL) ? 1 : 0;   // 1 => int32 layout
}

// ---------------------------------------------------------------------------
// Bitpack-transpose the mask: maskT[b][rt][key] = uint64, bit r set iff
// mask[b][rt*64 + r][key] != 0. Lane = row; int4 row loads (L1 reuses each
// 128B line 8x, HBM fetches mask exactly once); __ballot builds the word.
__global__ __launch_bounds__(64) void maskT_kernel(
    const void* __restrict__ mask, const int* __restrict__ flag_p,
    unsigned long long* __restrict__ maskT)
{
    int bid  = blockIdx.x;            // 8 * 32 * 16 blocks
    int ks   = bid & 15;
    int rt   = (bid >> 4) & 31;
    int b    = bid >> 9;
    int lane = threadIdx.x;
    size_t row = (size_t)b * S_LEN + rt * 64 + lane;
    int k0 = ks * 128;                // 128 keys per block
    unsigned long long* out = maskT + ((size_t)b * 32 + rt) * S_LEN + k0;

    if (flag_p[0]) {                  // int32 mask
        const int4* rp = (const int4*)((const int*)mask + row * S_LEN + k0);
#pragma unroll 4
        for (int j = 0; j < 32; ++j) {
            int4 v = rp[j];
            unsigned long long w0 = __ballot(v.x != 0);
            unsigned long long w1 = __ballot(v.y != 0);
            unsigned long long w2 = __ballot(v.z != 0);
            unsigned long long w3 = __ballot(v.w != 0);
            if (lane == 0) {
                out[j * 4 + 0] = w0; out[j * 4 + 1] = w1;
                out[j * 4 + 2] = w2; out[j * 4 + 3] = w3;
            }
        }
    } else {                          // 1-byte bool mask
        const int4* rp = (const int4*)((const unsigned char*)mask + row * S_LEN + k0);
#pragma unroll 2
        for (int j = 0; j < 8; ++j) {
            int4 v = rp[j];
            int wds[4] = {v.x, v.y, v.z, v.w};
#pragma unroll
            for (int wi = 0; wi < 4; ++wi) {
#pragma unroll
                for (int by = 0; by < 4; ++by) {
                    unsigned long long w = __ballot(((wds[wi] >> (8 * by)) & 255) != 0);
                    if (lane == 0) out[j * 16 + wi * 4 + by] = w;
                }
            }
        }
    }
}

// ---------------------------------------------------------------------------
// QKV projection: out = (x @ W + b) * scale.  Q gets 1/sqrt(8)*log2e folded in.
__global__ __launch_bounds__(256) void proj_kernel(
    const float* __restrict__ xQ, const float* __restrict__ xK,
    const float* __restrict__ xV,
    const float* __restrict__ WQ, const float* __restrict__ bQ,
    const float* __restrict__ WK, const float* __restrict__ bK,
    const float* __restrict__ WV, const float* __restrict__ bV,
    float* __restrict__ Qs, float* __restrict__ Ks, float* __restrict__ Vs)
{
    const float* x; const float* W; const float* bias; float* dst; float scale;
    if (blockIdx.y == 0)      { x = xQ; W = WQ; bias = bQ; dst = Qs; scale = QK_SCALE * LOG2E; }
    else if (blockIdx.y == 1) { x = xK; W = WK; bias = bK; dst = Ks; scale = 1.0f; }
    else                      { x = xV; W = WV; bias = bV; dst = Vs; scale = 1.0f; }

    __shared__ float xs[8][32];
    __shared__ float Ws[32][32];
    int t = threadIdx.x;
    long base = (long)blockIdx.x * 256;    // 8 rows x 32 cols
    xs[t >> 5][t & 31] = x[base + t];
#pragma unroll
    for (int i = 0; i < 4; ++i) {
        int f = i * 256 + t;
        Ws[f >> 5][f & 31] = W[f];
    }
    __syncthreads();
    int r = t >> 5, j = t & 31;
    float acc = bias[j];
#pragma unroll
    for (int i = 0; i < 32; ++i) acc = fmaf(xs[r][i], Ws[i][j], acc);
    dst[base + t] = acc * scale;
}

// ---------------------------------------------------------------------------
// Split-K flash attention, no-max variant (scores bounded, exp2 domain).
// 1 wave per block; lane -> (qg = lane>>2, h = lane&3); thread owns q-rows
// qg*4..qg*4+3 (wave covers 64 q-rows x 4 heads). K/V staged via LDS DMA,
// double-buffered, counted vmcnt. Mask: one wave-uniform uint64 per key from
// the bitpacked maskT (scalar-load path, no LDS, no DMA).
template<int NSEG>
__global__ __launch_bounds__(64, 4) void attn_kernel(
    const float* __restrict__ Qs, const float* __restrict__ Ks,
    const float* __restrict__ Vs, const unsigned long long* __restrict__ maskT,
    float* __restrict__ pl, float* __restrict__ pctx)
{
    constexpr int SEGLEN = S_LEN / NSEG;
    constexpr int NCH    = SEGLEN / CK;
    __shared__ float Kl[2][CK * 32];
    __shared__ float Vl[2][CK * 32];

    const int nb = NSEG * 32;                   // blocks per batch
    int raw = blockIdx.x;
    int cpx = (B_SZ * nb) / 8;
    int cid = (raw & 7) * cpx + (raw >> 3);     // XCD-contiguous (batch==XCD)
    int b   = cid / nb;
    int rem = cid - b * nb;
    int seg = rem >> 5;
    int qt  = rem & 31;
    int lane = threadIdx.x;

    int qg = lane >> 2, h = lane & 3;
    int tok0 = qt * 64;
    long tokbase = (long)b * S_LEN + tok0;
    int k0 = seg * SEGLEN;

    float4 qA[4], qB[4];
#pragma unroll
    for (int r = 0; r < 4; ++r) {
        const float* qp = Qs + (tokbase + qg * 4 + r) * 32 + h * 8;
        qA[r] = *(const float4*)qp;
        qB[r] = *(const float4*)(qp + 4);
    }

    const float* Kb = Ks + (long)b * S_LEN * 32;
    const float* Vb = Vs + (long)b * S_LEN * 32;
    const char* kg = (const char*)Kb + (size_t)k0 * 128 + lane * 16;
    const char* vg = (const char*)Vb + (size_t)k0 * 128 + lane * 16;
    const unsigned long long* mrow = maskT + ((size_t)b * 32 + qt) * S_LEN + k0;
    int shamt = qg * 4;

    // prologue: stage chunk 0 into buffer 0
    dma16(kg, &Kl[0][0]);
    dma16(vg, &Vl[0][0]);
    kg += CK * 128; vg += CK * 128;

    float l[4] = {0.f, 0.f, 0.f, 0.f};
    float c[4][8];
#pragma unroll
    for (int r = 0; r < 4; ++r)
#pragma unroll
        for (int e = 0; e < 8; ++e) c[r][e] = 0.f;

#pragma unroll 1
    for (int ch = 0; ch < NCH; ++ch) {
        int cur = ch & 1, nxt = cur ^ 1;

        if (ch + 1 < NCH) {
            dma16(kg, &Kl[nxt][0]);
            dma16(vg, &Vl[nxt][0]);
            kg += CK * 128; vg += CK * 128;
            asm volatile("s_waitcnt vmcnt(2)" ::: "memory");
        } else {
            asm volatile("s_waitcnt vmcnt(0)" ::: "memory");
        }

#pragma unroll
        for (int k = 0; k < CK; ++k) {
            const float* Kc = &Kl[cur][k * 32 + h * 8];
            float4 ka = *(const float4*)Kc;
            float4 kb = *(const float4*)(Kc + 4);
            const float* Vc = &Vl[cur][k * 32 + h * 8];
            float4 va = *(const float4*)Vc;
            float4 vb = *(const float4*)(Vc + 4);

            unsigned long long w = mrow[ch * CK + k];   // wave-uniform
            unsigned int u = (unsigned int)(w >> shamt);

            float p[4];
#pragma unroll
            for (int r = 0; r < 4; ++r) {
                float s = qA[r].x * ka.x;
                s = fmaf(qA[r].y, ka.y, s);
                s = fmaf(qA[r].z, ka.z, s);
                s = fmaf(qA[r].w, ka.w, s);
                s = fmaf(qB[r].x, kb.x, s);
                s = fmaf(qB[r].y, kb.y, s);
                s = fmaf(qB[r].z, kb.z, s);
                s = fmaf(qB[r].w, kb.w, s);
                if ((u >> r) & 1) s = MASKV;
                p[r] = exp2f(s);
                l[r] += p[r];
            }
#pragma unroll
            for (int r = 0; r < 4; ++r) {
                c[r][0] = fmaf(p[r], va.x, c[r][0]);
                c[r][1] = fmaf(p[r], va.y, c[r][1]);
                c[r][2] = fmaf(p[r], va.z, c[r][2]);
                c[r][3] = fmaf(p[r], va.w, c[r][3]);
                c[r][4] = fmaf(p[r], vb.x, c[r][4]);
                c[r][5] = fmaf(p[r], vb.y, c[r][5]);
                c[r][6] = fmaf(p[r], vb.z, c[r][6]);
                c[r][7] = fmaf(p[r], vb.w, c[r][7]);
            }
        }
    }

#pragma unroll
    for (int r = 0; r < 4; ++r) {
        long tok = tokbase + qg * 4 + r;
        pl[(size_t)seg * NTOK * 4 + tok * 4 + h] = l[r];
        float* pc = pctx + ((size_t)seg * NTOK + tok) * 32 + h * 8;
        *(float4*)(pc)     = make_float4(c[r][0], c[r][1], c[r][2], c[r][3]);
        *(float4*)(pc + 4) = make_float4(c[r][4], c[r][5], c[r][6], c[r][7]);
    }
}

// ---------------------------------------------------------------------------
// Merge split-K partials (plain sums; no max needed) -> sa; then
// attn_output = sa@WO + bO + resid; LayerNorm.
template<int NSEG>
__global__ __launch_bounds__(256) void combine_epilogue(
    const float* __restrict__ pl, const float* __restrict__ pctx,
    const float* __restrict__ WO, const float* __restrict__ bO,
    const float* __restrict__ resid,
    float* __restrict__ sa_out, float* __restrict__ out0)
{
    __shared__ float sas[8][32];
    __shared__ float Ws[32][32];
    int t = threadIdx.x;
    long base = (long)blockIdx.x * 256;      // 8 tokens x 32
    int r = t >> 5, j = t & 31;
    long tok = (long)blockIdx.x * 8 + r;
    int h = j >> 3;

#pragma unroll
    for (int i = 0; i < 4; ++i) {
        int f = i * 256 + t;
        Ws[f >> 5][f & 31] = WO[f];
    }

    float L = 0.f, ctx = 0.f;
#pragma unroll
    for (int s2 = 0; s2 < NSEG; ++s2) {
        L   += pl[(size_t)s2 * NTOK * 4 + tok * 4 + h];
        ctx += pctx[((size_t)s2 * NTOK + tok) * 32 + j];
    }
    float sa = ctx / L;
    sa_out[base + t] = sa;
    sas[r][j] = sa;
    __syncthreads();

    float y = bO[j] + resid[base + t];
#pragma unroll
    for (int i = 0; i < 32; ++i) y = fmaf(sas[r][i], Ws[i][j], y);

    float sum = y;
#pragma unroll
    for (int o = 16; o >= 1; o >>= 1) sum += __shfl_xor(sum, o, 32);
    float mu = sum * (1.0f / 32.0f);
    float d  = y - mu;
    float sq = d * d;
#pragma unroll
    for (int o = 16; o >= 1; o >>= 1) sq += __shfl_xor(sq, o, 32);
    float var = sq * (1.0f / 32.0f);
    out0[base + t] = d * rsqrtf(var + LN_EPS);
}

// ---------------------------------------------------------------------------
extern "C" void kernel_launch(void* const* d_in, const int* in_sizes, int n_in,
                              void* d_out, int out_size, void* d_ws, size_t ws_size,
                              hipStream_t stream)
{
    const float* inQ = (const float*)d_in[0];
    const float* inK = (const float*)d_in[1];
    const float* inV = (const float*)d_in[2];
    const void*  mask = d_in[3];
    const float* WQ = (const float*)d_in[4];
    const float* bQ = (const float*)d_in[5];
    const float* WK = (const float*)d_in[6];
    const float* bK = (const float*)d_in[7];
    const float* WV = (const float*)d_in[8];
    const float* bV = (const float*)d_in[9];
    const float* WO = (const float*)d_in[10];
    const float* bO = (const float*)d_in[11];

    float* out0 = (float*)d_out;                    // layernorm output
    float* sa   = (float*)d_out + (long)NTOK * 32;  // self_attn output

    char* ws   = (char*)d_ws;
    int*  flag = (int*)ws;
    float* Qs  = (float*)(ws + 256);
    float* Ks  = Qs + (long)NTOK * 32;
    float* Vs  = Ks + (long)NTOK * 32;
    unsigned long long* maskT = (unsigned long long*)(Vs + (long)NTOK * 32);
    float* pbase = (float*)(maskT + (size_t)B_SZ * 32 * S_LEN);

    // per-seg partials: pl (NTOK*4) + pctx (NTOK*32) floats
    size_t fixed  = 256 + 3ul * NTOK * 32 * 4 + (size_t)B_SZ * 32 * S_LEN * 8;
    size_t perseg = (size_t)NTOK * 36 * 4;
    int NS = 1;
    if      (fixed + 16 * perseg <= ws_size) NS = 16;
    else if (fixed +  8 * perseg <= ws_size) NS = 8;
    else if (fixed +  4 * perseg <= ws_size) NS = 4;
    else if (fixed +  2 * perseg <= ws_size) NS = 2;

    float* pl   = pbase;
    float* pctx = pl + (long)NS * NTOK * 4;

    detect_mask_dtype<<<1, 64, 0, stream>>>((const unsigned char*)mask, flag);
    maskT_kernel<<<B_SZ * 32 * 16, 64, 0, stream>>>(mask, flag, maskT);
    proj_kernel<<<dim3(NTOK / 8, 3), 256, 0, stream>>>(
        inQ, inK, inV, WQ, bQ, WK, bK, WV, bV, Qs, Ks, Vs);

    int agrid = B_SZ * NS * 32;
    int cgrid = NTOK / 8;
    switch (NS) {
    case 16:
        attn_kernel<16><<<agrid, 64, 0, stream>>>(Qs, Ks, Vs, maskT, pl, pctx);
        combine_epilogue<16><<<cgrid, 256, 0, stream>>>(pl, pctx, WO, bO, inQ, sa, out0);
        break;
    case 8:
        attn_kernel<8><<<agrid, 64, 0, stream>>>(Qs, Ks, Vs, maskT, pl, pctx);
        combine_epilogue<8><<<cgrid, 256, 0, stream>>>(pl, pctx, WO, bO, inQ, sa, out0);
        break;
    case 4:
        attn_kernel<4><<<agrid, 64, 0, stream>>>(Qs, Ks, Vs, maskT, pl, pctx);
        combine_epilogue<4><<<cgrid, 256, 0, stream>>>(pl, pctx, WO, bO, inQ, sa, out0);
        break;
    case 2:
        attn_kernel<2><<<agrid, 64, 0, stream>>>(Qs, Ks, Vs, maskT, pl, pctx);
        combine_epilogue<2><<<cgrid, 256, 0, stream>>>(pl, pctx, WO, bO, inQ, sa, out0);
        break;
    default:
        attn_kernel<1><<<agrid, 64, 0, stream>>>(Qs, Ks, Vs, maskT, pl, pctx);
        combine_epilogue<1><<<cgrid, 256, 0, stream>>>(pl, pctx, WO, bO, inQ, sa, out0);
        break;
    }
}

// Round 6
// 117.957 us; speedup vs baseline: 1.8993x; 1.8993x over previous
//
#include <hip/hip_runtime.h>
#include <hip/hip_bf16.h>
#include <math.h>

#define D_MODEL 32
#define S_LEN   2048
#define B_SZ    8
#define NTOK    (B_SZ * S_LEN)
#define LN_EPS  1e-5f
#define LOG2E   1.44269504088896340736f
#define QK_SCALE 0.35355339059327373f   /* 1/sqrt(8) */
#define MASKV   (-1.0e9f)               /* v_exp_f32(-1e9) == 0 */
#define CK      8                        /* keys per DMA chunk */

typedef const __attribute__((address_space(1))) void* gp_t;
typedef __attribute__((address_space(3))) void* sp_t;
typedef float v2f __attribute__((ext_vector_type(2)));

__device__ __forceinline__ void dma16(const void* g, void* s) {
    __builtin_amdgcn_global_load_lds((gp_t)g, (sp_t)s, 16, 0, 0);
}
__device__ __forceinline__ v2f sp2(float x) { v2f r; r.x = x; r.y = x; return r; }

// ---------------------------------------------------------------------------
__global__ void detect_mask_dtype(const unsigned char* __restrict__ mb,
                                  int* __restrict__ flag) {
    int t = threadIdx.x;  // 64 lanes
    unsigned char b1 = mb[t * 4 + 1];
    unsigned char b2 = mb[t * 4 + 2];
    unsigned char b3 = mb[t * 4 + 3];
    int ok = ((b1 | b2 | b3) == 0);
    unsigned long long vote = __ballot(ok);
    if (t == 0) flag[0] = (vote == ~0ULL) ? 1 : 0;   // 1 => int32 layout
}

// ---------------------------------------------------------------------------
// Bitpack-transpose the mask, 64x64 tiles, fully coalesced:
//   stage tile rows to LDS (coalesced int4 reads, every line consumed once),
//   column-read from LDS (padded, conflict-free), per-lane 64-bit build,
//   coalesced uint64 store. maskT[b][rt][key] bit r = mask[b][rt*64+r][key].
__global__ __launch_bounds__(64) void maskT_kernel(
    const void* __restrict__ mask, const int* __restrict__ flag_p,
    unsigned long long* __restrict__ maskT)
{
    __shared__ int Msh[64 * 68];      // int path: [64][68] pad -> conflict-free cols
    int bid  = blockIdx.x;            // 8 * 32 * 32
    int kt   = bid & 31;
    int rt   = (bid >> 5) & 31;
    int b    = bid >> 10;
    int lane = threadIdx.x;
    int r0 = rt * 64, k0 = kt * 64;

    unsigned long long w = 0;

    if (flag_p[0]) {                  // ---- int32 mask
        const int* m32 = (const int*)mask;
#pragma unroll
        for (int p = 0; p < 16; ++p) {
            int row = p * 4 + (lane >> 4);
            int c   = (lane & 15) * 4;
            int4 v = *(const int4*)(m32 + ((size_t)b * S_LEN + r0 + row) * S_LEN + k0 + c);
            *(int4*)&Msh[row * 68 + c] = v;
        }
        unsigned lo = 0, hi = 0;
#pragma unroll
        for (int r = 0; r < 32; ++r)
            if (Msh[r * 68 + lane]) lo |= (1u << r);
#pragma unroll
        for (int r = 0; r < 32; ++r)
            if (Msh[(r + 32) * 68 + lane]) hi |= (1u << r);
        w = ((unsigned long long)hi << 32) | lo;
    } else {                          // ---- 1-byte bool mask
        unsigned char* Mb = (unsigned char*)Msh;   // [64][80] pad
        const unsigned char* m8 = (const unsigned char*)mask;
#pragma unroll
        for (int p = 0; p < 4; ++p) {
            int row = p * 16 + (lane >> 2);
            int c   = (lane & 3) * 16;
            int4 v = *(const int4*)(m8 + ((size_t)b * S_LEN + r0 + row) * S_LEN + k0 + c);
            *(int4*)&Mb[row * 80 + c] = v;
        }
        unsigned lo = 0, hi = 0;
#pragma unroll
        for (int r = 0; r < 32; ++r)
            if (Mb[r * 80 + lane]) lo |= (1u << r);
#pragma unroll
        for (int r = 0; r < 32; ++r)
            if (Mb[(r + 32) * 80 + lane]) hi |= (1u << r);
        w = ((unsigned long long)hi << 32) | lo;
    }

    maskT[((size_t)b * 32 + rt) * S_LEN + k0 + lane] = w;
}

// ---------------------------------------------------------------------------
// QKV projection: out = (x @ W + b) * scale.  Q gets 1/sqrt(8)*log2e folded in.
__global__ __launch_bounds__(256) void proj_kernel(
    const float* __restrict__ xQ, const float* __restrict__ xK,
    const float* __restrict__ xV,
    const float* __restrict__ WQ, const float* __restrict__ bQ,
    const float* __restrict__ WK, const float* __restrict__ bK,
    const float* __restrict__ WV, const float* __restrict__ bV,
    float* __restrict__ Qs, float* __restrict__ Ks, float* __restrict__ Vs)
{
    const float* x; const float* W; const float* bias; float* dst; float scale;
    if (blockIdx.y == 0)      { x = xQ; W = WQ; bias = bQ; dst = Qs; scale = QK_SCALE * LOG2E; }
    else if (blockIdx.y == 1) { x = xK; W = WK; bias = bK; dst = Ks; scale = 1.0f; }
    else                      { x = xV; W = WV; bias = bV; dst = Vs; scale = 1.0f; }

    __shared__ float xs[8][32];
    __shared__ float Ws[32][32];
    int t = threadIdx.x;
    long base = (long)blockIdx.x * 256;    // 8 rows x 32 cols
    xs[t >> 5][t & 31] = x[base + t];
#pragma unroll
    for (int i = 0; i < 4; ++i) {
        int f = i * 256 + t;
        Ws[f >> 5][f & 31] = W[f];
    }
    __syncthreads();
    int r = t >> 5, j = t & 31;
    float acc = bias[j];
#pragma unroll
    for (int i = 0; i < 32; ++i) acc = fmaf(xs[r][i], Ws[i][j], acc);
    dst[base + t] = acc * scale;
}

// ---------------------------------------------------------------------------
// Split-K flash attention, no-max variant (scores bounded, exp2 domain).
// 1 wave per block; lane -> (qg = lane>>2, h = lane&3); thread owns q-rows
// qg*4..qg*4+3 processed as TWO row-pairs in v2f (targets v_pk_fma_f32).
// K/V staged via LDS DMA, double-buffered, counted vmcnt. Mask: wave-uniform
// uint64 per key from bitpacked maskT. exp2 via raw v_exp_f32.
template<int NSEG>
__global__ __launch_bounds__(64, 4) void attn_kernel(
    const float* __restrict__ Qs, const float* __restrict__ Ks,
    const float* __restrict__ Vs, const unsigned long long* __restrict__ maskT,
    float* __restrict__ pl, float* __restrict__ pctx)
{
    constexpr int SEGLEN = S_LEN / NSEG;
    constexpr int NCH    = SEGLEN / CK;
    __shared__ float Kl[2][CK * 32];
    __shared__ float Vl[2][CK * 32];

    const int nb = NSEG * 32;                   // blocks per batch
    int raw = blockIdx.x;
    int cpx = (B_SZ * nb) / 8;
    int cid = (raw & 7) * cpx + (raw >> 3);     // XCD-contiguous (batch==XCD)
    int b   = cid / nb;
    int rem = cid - b * nb;
    int seg = rem >> 5;
    int qt  = rem & 31;
    int lane = threadIdx.x;

    int qg = lane >> 2, h = lane & 3;
    int tok0 = qt * 64;
    long tokbase = (long)b * S_LEN + tok0;
    int k0 = seg * SEGLEN;

    // Q rows as row-pairs: q2[pr][e] = {Q[row 2pr][e], Q[row 2pr+1][e]}
    v2f q2[2][8];
#pragma unroll
    for (int r = 0; r < 4; ++r) {
        const float* qp = Qs + (tokbase + qg * 4 + r) * 32 + h * 8;
        float4 a = *(const float4*)qp;
        float4 bq = *(const float4*)(qp + 4);
        float e[8] = {a.x, a.y, a.z, a.w, bq.x, bq.y, bq.z, bq.w};
        int pr = r >> 1;
#pragma unroll
        for (int j = 0; j < 8; ++j) {
            if ((r & 1) == 0) q2[pr][j].x = e[j];
            else              q2[pr][j].y = e[j];
        }
    }

    const float* Kb = Ks + (long)b * S_LEN * 32;
    const float* Vb = Vs + (long)b * S_LEN * 32;
    const char* kg = (const char*)Kb + (size_t)k0 * 128 + lane * 16;
    const char* vg = (const char*)Vb + (size_t)k0 * 128 + lane * 16;
    const unsigned long long* mrow = maskT + ((size_t)b * 32 + qt) * S_LEN + k0;
    int shamt = qg * 4;

    // prologue: stage chunk 0 into buffer 0
    dma16(kg, &Kl[0][0]);
    dma16(vg, &Vl[0][0]);
    kg += CK * 128; vg += CK * 128;

    v2f l2[2] = {{0.f, 0.f}, {0.f, 0.f}};
    v2f c2[2][8];
#pragma unroll
    for (int pr = 0; pr < 2; ++pr)
#pragma unroll
        for (int e = 0; e < 8; ++e) { c2[pr][e].x = 0.f; c2[pr][e].y = 0.f; }

#pragma unroll 1
    for (int ch = 0; ch < NCH; ++ch) {
        int cur = ch & 1, nxt = cur ^ 1;

        if (ch + 1 < NCH) {
            dma16(kg, &Kl[nxt][0]);
            dma16(vg, &Vl[nxt][0]);
            kg += CK * 128; vg += CK * 128;
            asm volatile("s_waitcnt vmcnt(2)" ::: "memory");
        } else {
            asm volatile("s_waitcnt vmcnt(0)" ::: "memory");
        }

#pragma unroll
        for (int k = 0; k < CK; ++k) {
            const float* Kc = &Kl[cur][k * 32 + h * 8];
            float4 ka = *(const float4*)Kc;
            float4 kb = *(const float4*)(Kc + 4);
            const float* Vc = &Vl[cur][k * 32 + h * 8];
            float4 va = *(const float4*)Vc;
            float4 vb = *(const float4*)(Vc + 4);
            float Ke[8] = {ka.x, ka.y, ka.z, ka.w, kb.x, kb.y, kb.z, kb.w};
            float Ve[8] = {va.x, va.y, va.z, va.w, vb.x, vb.y, vb.z, vb.w};

            unsigned long long w = mrow[ch * CK + k];   // wave-uniform
            unsigned int u = (unsigned int)(w >> shamt);

            v2f p2[2];
#pragma unroll
            for (int pr = 0; pr < 2; ++pr) {
                v2f s = q2[pr][0] * sp2(Ke[0]);
#pragma unroll
                for (int e = 1; e < 8; ++e)
                    s = __builtin_elementwise_fma(q2[pr][e], sp2(Ke[e]), s);
                s.x = ((u >> (pr * 2))     & 1) ? MASKV : s.x;
                s.y = ((u >> (pr * 2 + 1)) & 1) ? MASKV : s.y;
                p2[pr].x = __builtin_amdgcn_exp2f(s.x);
                p2[pr].y = __builtin_amdgcn_exp2f(s.y);
                l2[pr] += p2[pr];
#pragma unroll
                for (int e = 0; e < 8; ++e)
                    c2[pr][e] = __builtin_elementwise_fma(p2[pr], sp2(Ve[e]), c2[pr][e]);
            }
        }
    }

#pragma unroll
    for (int r = 0; r < 4; ++r) {
        int pr = r >> 1;
        int hi = r & 1;
        long tok = tokbase + qg * 4 + r;
        float lv = hi ? l2[pr].y : l2[pr].x;
        pl[(size_t)seg * NTOK * 4 + tok * 4 + h] = lv;
        float cv[8];
#pragma unroll
        for (int e = 0; e < 8; ++e) cv[e] = hi ? c2[pr][e].y : c2[pr][e].x;
        float* pc = pctx + ((size_t)seg * NTOK + tok) * 32 + h * 8;
        *(float4*)(pc)     = make_float4(cv[0], cv[1], cv[2], cv[3]);
        *(float4*)(pc + 4) = make_float4(cv[4], cv[5], cv[6], cv[7]);
    }
}

// ---------------------------------------------------------------------------
// Merge split-K partials (plain sums; no max needed) -> sa; then
// attn_output = sa@WO + bO + resid; LayerNorm.
template<int NSEG>
__global__ __launch_bounds__(256) void combine_epilogue(
    const float* __restrict__ pl, const float* __restrict__ pctx,
    const float* __restrict__ WO, const float* __restrict__ bO,
    const float* __restrict__ resid,
    float* __restrict__ sa_out, float* __restrict__ out0)
{
    __shared__ float sas[8][32];
    __shared__ float Ws[32][32];
    int t = threadIdx.x;
    long base = (long)blockIdx.x * 256;      // 8 tokens x 32
    int r = t >> 5, j = t & 31;
    long tok = (long)blockIdx.x * 8 + r;
    int h = j >> 3;

#pragma unroll
    for (int i = 0; i < 4; ++i) {
        int f = i * 256 + t;
        Ws[f >> 5][f & 31] = WO[f];
    }

    float L = 0.f, ctx = 0.f;
#pragma unroll
    for (int s2 = 0; s2 < NSEG; ++s2) {
        L   += pl[(size_t)s2 * NTOK * 4 + tok * 4 + h];
        ctx += pctx[((size_t)s2 * NTOK + tok) * 32 + j];
    }
    float sa = ctx / L;
    sa_out[base + t] = sa;
    sas[r][j] = sa;
    __syncthreads();

    float y = bO[j] + resid[base + t];
#pragma unroll
    for (int i = 0; i < 32; ++i) y = fmaf(sas[r][i], Ws[i][j], y);

    float sum = y;
#pragma unroll
    for (int o = 16; o >= 1; o >>= 1) sum += __shfl_xor(sum, o, 32);
    float mu = sum * (1.0f / 32.0f);
    float d  = y - mu;
    float sq = d * d;
#pragma unroll
    for (int o = 16; o >= 1; o >>= 1) sq += __shfl_xor(sq, o, 32);
    float var = sq * (1.0f / 32.0f);
    out0[base + t] = d * rsqrtf(var + LN_EPS);
}

// ---------------------------------------------------------------------------
extern "C" void kernel_launch(void* const* d_in, const int* in_sizes, int n_in,
                              void* d_out, int out_size, void* d_ws, size_t ws_size,
                              hipStream_t stream)
{
    const float* inQ = (const float*)d_in[0];
    const float* inK = (const float*)d_in[1];
    const float* inV = (const float*)d_in[2];
    const void*  mask = d_in[3];
    const float* WQ = (const float*)d_in[4];
    const float* bQ = (const float*)d_in[5];
    const float* WK = (const float*)d_in[6];
    const float* bK = (const float*)d_in[7];
    const float* WV = (const float*)d_in[8];
    const float* bV = (const float*)d_in[9];
    const float* WO = (const float*)d_in[10];
    const float* bO = (const float*)d_in[11];

    float* out0 = (float*)d_out;                    // layernorm output
    float* sa   = (float*)d_out + (long)NTOK * 32;  // self_attn output

    char* ws   = (char*)d_ws;
    int*  flag = (int*)ws;
    float* Qs  = (float*)(ws + 256);
    float* Ks  = Qs + (long)NTOK * 32;
    float* Vs  = Ks + (long)NTOK * 32;
    unsigned long long* maskT = (unsigned long long*)(Vs + (long)NTOK * 32);
    float* pbase = (float*)(maskT + (size_t)B_SZ * 32 * S_LEN);

    // per-seg partials: pl (NTOK*4) + pctx (NTOK*32) floats
    size_t fixed  = 256 + 3ul * NTOK * 32 * 4 + (size_t)B_SZ * 32 * S_LEN * 8;
    size_t perseg = (size_t)NTOK * 36 * 4;
    int NS = 1;
    if      (fixed + 16 * perseg <= ws_size) NS = 16;
    else if (fixed +  8 * perseg <= ws_size) NS = 8;
    else if (fixed +  4 * perseg <= ws_size) NS = 4;
    else if (fixed +  2 * perseg <= ws_size) NS = 2;

    float* pl   = pbase;
    float* pctx = pl + (long)NS * NTOK * 4;

    detect_mask_dtype<<<1, 64, 0, stream>>>((const unsigned char*)mask, flag);
    maskT_kernel<<<B_SZ * 32 * 32, 64, 0, stream>>>(mask, flag, maskT);
    proj_kernel<<<dim3(NTOK / 8, 3), 256, 0, stream>>>(
        inQ, inK, inV, WQ, bQ, WK, bK, WV, bV, Qs, Ks, Vs);

    int agrid = B_SZ * NS * 32;
    int cgrid = NTOK / 8;
    switch (NS) {
    case 16:
        attn_kernel<16><<<agrid, 64, 0, stream>>>(Qs, Ks, Vs, maskT, pl, pctx);
        combine_epilogue<16><<<cgrid, 256, 0, stream>>>(pl, pctx, WO, bO, inQ, sa, out0);
        break;
    case 8:
        attn_kernel<8><<<agrid, 64, 0, stream>>>(Qs, Ks, Vs, maskT, pl, pctx);
        combine_epilogue<8><<<cgrid, 256, 0, stream>>>(pl, pctx, WO, bO, inQ, sa, out0);
        break;
    case 4:
        attn_kernel<4><<<agrid, 64, 0, stream>>>(Qs, Ks, Vs, maskT, pl, pctx);
        combine_epilogue<4><<<cgrid, 256, 0, stream>>>(pl, pctx, WO, bO, inQ, sa, out0);
        break;
    case 2:
        attn_kernel<2><<<agrid, 64, 0, stream>>>(Qs, Ks, Vs, maskT, pl, pctx);
        combine_epilogue<2><<<cgrid, 256, 0, stream>>>(pl, pctx, WO, bO, inQ, sa, out0);
        break;
    default:
        attn_kernel<1><<<agrid, 64, 0, stream>>>(Qs, Ks, Vs, maskT, pl, pctx);
        combine_epilogue<1><<<cgrid, 256, 0, stream>>>(pl, pctx, WO, bO, inQ, sa, out0);
        break;
    }
}

// Round 8
// 102.625 us; speedup vs baseline: 2.1831x; 1.1494x over previous
//
#include <hip/hip_runtime.h>
#include <math.h>

#define D_MODEL 32
#define S_LEN   2048
#define B_SZ    8
#define NTOK    (B_SZ * S_LEN)
#define LN_EPS  1e-5f
#define LOG2E   1.44269504088896340736f
#define QK_SCALE 0.35355339059327373f   /* 1/sqrt(8) */
#define MASKV   (-1.0e9f)               /* v_exp_f32(-1e9) == 0 */

typedef __attribute__((ext_vector_type(8)))  short    short8b;
typedef __attribute__((ext_vector_type(4)))  short    short4b;
typedef __attribute__((ext_vector_type(4)))  unsigned uint4v;
typedef __attribute__((ext_vector_type(16))) float    f32x16;

__device__ __forceinline__ unsigned short f2bf(float f) {   // RNE f32->bf16
    unsigned u = __builtin_bit_cast(unsigned, f);
    unsigned r = (u + 0x7FFFu + ((u >> 16) & 1u)) >> 16;
    return (unsigned short)r;
}
__device__ __forceinline__ float bf2f(unsigned short h) {
    return __builtin_bit_cast(float, (unsigned)h << 16);
}
__device__ __forceinline__ unsigned cvtpk_bf16(float lo, float hi) {
    unsigned r;
    asm("v_cvt_pk_bf16_f32 %0, %1, %2" : "=v"(r) : "v"(lo), "v"(hi));
    return r;
}

// ---------------------------------------------------------------------------
__global__ void detect_mask_dtype(const unsigned char* __restrict__ mb,
                                  int* __restrict__ flag) {
    int t = threadIdx.x;  // 64 lanes
    unsigned char b1 = mb[t * 4 + 1];
    unsigned char b2 = mb[t * 4 + 2];
    unsigned char b3 = mb[t * 4 + 3];
    int ok = ((b1 | b2 | b3) == 0);
    unsigned long long vote = __ballot(ok);
    if (t == 0) flag[0] = (vote == ~0ULL) ? 1 : 0;   // 1 => int32 layout
}

// ---------------------------------------------------------------------------
// Row-bitpack the mask (no transpose): pack[tok][w] bit j = mask[tok][64w+j]!=0.
__global__ __launch_bounds__(256) void maskpack_kernel(
    const void* __restrict__ mask, const int* __restrict__ flag_p,
    unsigned long long* __restrict__ pack)
{
    int tid = threadIdx.x;
    long row = (long)blockIdx.x * 4 + (tid >> 6);
    int lane = tid & 63;
    unsigned long long* prow = pack + row * (S_LEN / 64);
    if (flag_p[0]) {
        const int* mr = (const int*)mask + row * S_LEN;
#pragma unroll 4
        for (int it = 0; it < 32; ++it) {
            unsigned long long wv = __ballot(mr[it * 64 + lane] != 0);
            if (lane == 0) prow[it] = wv;
        }
    } else {
        const unsigned char* mr = (const unsigned char*)mask + row * S_LEN;
#pragma unroll 4
        for (int it = 0; it < 32; ++it) {
            unsigned long long wv = __ballot(mr[it * 64 + lane] != 0);
            if (lane == 0) prow[it] = wv;
        }
    }
}

// ---------------------------------------------------------------------------
// QKV projection. Q (pre-scaled by 1/sqrt(8)*log2e) and K are stored as
// SPLIT bf16 (hi = bf16(x), lo = bf16(x - hi)) so QK^T can be computed
// exactly with two MFMAs. V stored transposed per head, single bf16.
__global__ __launch_bounds__(256) void proj_kernel(
    const float* __restrict__ xQ, const float* __restrict__ xK,
    const float* __restrict__ xV,
    const float* __restrict__ WQ, const float* __restrict__ bQ,
    const float* __restrict__ WK, const float* __restrict__ bK,
    const float* __restrict__ WV, const float* __restrict__ bV,
    unsigned short* __restrict__ Qh, unsigned short* __restrict__ Ql,
    unsigned short* __restrict__ Kh, unsigned short* __restrict__ Kl,
    unsigned short* __restrict__ Vt)
{
    const float* x; const float* W; const float* bias; float scale;
    if (blockIdx.y == 0)      { x = xQ; W = WQ; bias = bQ; scale = QK_SCALE * LOG2E; }
    else if (blockIdx.y == 1) { x = xK; W = WK; bias = bK; scale = 1.0f; }
    else                      { x = xV; W = WV; bias = bV; scale = 1.0f; }

    __shared__ float xs[8][32];
    __shared__ float Ws[32][32];
    int t = threadIdx.x;
    long base = (long)blockIdx.x * 256;    // 8 rows x 32 cols
    xs[t >> 5][t & 31] = x[base + t];
#pragma unroll
    for (int i = 0; i < 4; ++i) {
        int f = i * 256 + t;
        Ws[f >> 5][f & 31] = W[f];
    }
    __syncthreads();
    int r = t >> 5, j = t & 31;
    float acc = bias[j];
#pragma unroll
    for (int i = 0; i < 32; ++i) acc = fmaf(xs[r][i], Ws[i][j], acc);
    acc *= scale;

    if (blockIdx.y == 0) {
        unsigned short hv = f2bf(acc);
        Qh[base + t] = hv;
        Ql[base + t] = f2bf(acc - bf2f(hv));
    } else if (blockIdx.y == 1) {
        unsigned short hv = f2bf(acc);
        Kh[base + t] = hv;
        Kl[base + t] = f2bf(acc - bf2f(hv));
    } else {
        long tok = (long)blockIdx.x * 8 + r;
        long b   = tok >> 11;
        long ti  = tok & (S_LEN - 1);
        int  h   = j >> 3, dv = j & 7;
        Vt[((b * 4 + h) * 8 + dv) * S_LEN + ti] = f2bf(acc);
    }
}

// ---------------------------------------------------------------------------
// MFMA flash attention (no-max, exp2 domain, split-K, EXACT QK via split-bf16).
// Wave = (b, seg, 32-q tile), all 4 heads. Per 32-key chunk, per head:
//   A = [K_hi | K_lo] (lane-half selects hi/lo), B1 = [Q_hi|Q_hi], B2=[Q_lo|Q_lo]
//   S^T = mfma(A,B1,0); S^T = mfma(A,B2,S^T)   => exact q.k in f32
//   p = exp2(S^T + mask) -> cvt_pk bf16 -> PV B-operand directly;
//   ctx^T += mfma(A=V^T rows (dv + ones), B=P^T) with matching k-slot perm.
template<int NSEG>
__global__ __launch_bounds__(256) void attn_kernel(
    const unsigned short* __restrict__ Qh, const unsigned short* __restrict__ Ql,
    const unsigned short* __restrict__ Kh, const unsigned short* __restrict__ Kl,
    const unsigned short* __restrict__ Vt,
    const unsigned long long* __restrict__ pack,
    float* __restrict__ pl, float* __restrict__ pctx)
{
    constexpr int SEGLEN = S_LEN / NSEG;
    constexpr int NCH    = SEGLEN / 32;
    const int nb    = NSEG * 16;            // blocks per batch (4 waves/block)
    int raw   = blockIdx.x;
    int total = B_SZ * nb;
    int cpx   = total >> 3;
    int cid   = (raw & 7) * cpx + (raw >> 3);   // XCD-contiguous
    int b     = cid / nb;
    int rem   = cid - b * nb;
    int seg   = rem >> 4;
    int qt    = (rem & 15) * 4 + (threadIdx.x >> 6);
    int lane  = threadIdx.x & 63;
    int q     = lane & 31;
    int half  = lane >> 5;
    int tok0  = qt * 32;
    long tokq = (long)b * S_LEN + tok0 + q;
    int k0    = seg * SEGLEN;

    // Q fragments: BOTH halves load the same values => B = [Qh|Qh], [Ql|Ql].
    short8b qhf[4], qlf[4];
#pragma unroll
    for (int h = 0; h < 4; ++h) {
        qhf[h] = *(const short8b*)(Qh + tokq * 32 + h * 8);
        qlf[h] = *(const short8b*)(Ql + tokq * 32 + h * 8);
    }

    f32x16 zero16;
#pragma unroll
    for (int i = 0; i < 16; ++i) zero16[i] = 0.0f;
    f32x16 cpv[4];
#pragma unroll
    for (int h = 0; h < 4; ++h) cpv[h] = zero16;

    const unsigned long long* prow = pack + tokq * (S_LEN / 64);
    const unsigned short* Ksel = (half ? Kl : Kh) + (long)b * S_LEN * 32;

    unsigned long long w = 0;
#pragma unroll 1
    for (int ch = 0; ch < NCH; ++ch) {
        int kc = k0 + ch * 32;
        if ((ch & 1) == 0) w = prow[kc >> 6];
        unsigned wh  = (ch & 1) ? (unsigned)(w >> 32) : (unsigned)w;
        unsigned wsh = wh >> (half * 4);
        float madd[16];
#pragma unroll
        for (int r = 0; r < 16; ++r) {
            const int cr = (r & 3) + 8 * (r >> 2);
            madd[r] = ((wsh >> cr) & 1u) ? MASKV : 0.0f;
        }

#pragma unroll
        for (int h = 0; h < 4; ++h) {
            // A rows m=lane&31 -> key kc+q; half 0 supplies K_hi at k-slots
            // 0-7 (d0-7), half 1 supplies K_lo at k-slots 8-15 (same d0-7).
            short8b kf = *(const short8b*)(Ksel + (long)(kc + q) * 32 + h * 8);
            f32x16 acc = __builtin_amdgcn_mfma_f32_32x32x16_bf16(kf, qhf[h], zero16, 0, 0, 0);
            acc = __builtin_amdgcn_mfma_f32_32x32x16_bf16(kf, qlf[h], acc, 0, 0, 0);

            unsigned pr[8];
#pragma unroll
            for (int j = 0; j < 8; ++j) {
                float p0 = __builtin_amdgcn_exp2f(acc[2 * j]     + madd[2 * j]);
                float p1 = __builtin_amdgcn_exp2f(acc[2 * j + 1] + madd[2 * j + 1]);
                pr[j] = cvtpk_bf16(p0, p1);
            }
            uint4v t1, t2;
            t1.x = pr[0]; t1.y = pr[1]; t1.z = pr[2]; t1.w = pr[3];
            t2.x = pr[4]; t2.y = pr[5]; t2.z = pr[6]; t2.w = pr[7];
            short8b pb1 = __builtin_bit_cast(short8b, t1);
            short8b pb2 = __builtin_bit_cast(short8b, t2);

            // V^T A-frags mirror P's (half, elem)->key mapping exactly, so the
            // shared k-slot permutation cancels regardless of HW slot order.
            short8b vf1, vf2;
            if (q < 8) {
                const unsigned short* vr =
                    Vt + (((long)b * 4 + h) * 8 + q) * S_LEN + kc + half * 4;
                short4b a0 = *(const short4b*)(vr);
                short4b a1 = *(const short4b*)(vr + 8);
                short4b a2 = *(const short4b*)(vr + 16);
                short4b a3 = *(const short4b*)(vr + 24);
                vf1 = __builtin_shufflevector(a0, a1, 0, 1, 2, 3, 4, 5, 6, 7);
                vf2 = __builtin_shufflevector(a2, a3, 0, 1, 2, 3, 4, 5, 6, 7);
            } else {
                short ov = (q == 8) ? (short)0x3F80 : (short)0;  // ones row -> l-sum
#pragma unroll
                for (int i = 0; i < 8; ++i) { vf1[i] = ov; vf2[i] = ov; }
            }
            cpv[h] = __builtin_amdgcn_mfma_f32_32x32x16_bf16(vf1, pb1, cpv[h], 0, 0, 0);
            cpv[h] = __builtin_amdgcn_mfma_f32_32x32x16_bf16(vf2, pb2, cpv[h], 0, 0, 0);
        }
    }

    // C_PV: col=q; lower half regs0-3 = dv0-3, reg4 = row8 = l-sum;
    // upper half regs0-3 = dv4-7.
#pragma unroll
    for (int h = 0; h < 4; ++h) {
        float4 cv = make_float4(cpv[h][0], cpv[h][1], cpv[h][2], cpv[h][3]);
        *(float4*)(pctx + ((size_t)seg * NTOK + tokq) * 32 + h * 8 + half * 4) = cv;
        if (half == 0)
            pl[(size_t)seg * NTOK * 4 + tokq * 4 + h] = cpv[h][4];
    }
}

// ---------------------------------------------------------------------------
// Merge split-K partials (plain sums) -> sa; attn_out = sa@WO + bO + resid; LN.
template<int NSEG>
__global__ __launch_bounds__(256) void combine_epilogue(
    const float* __restrict__ pl, const float* __restrict__ pctx,
    const float* __restrict__ WO, const float* __restrict__ bO,
    const float* __restrict__ resid,
    float* __restrict__ sa_out, float* __restrict__ out0)
{
    __shared__ float sas[8][32];
    __shared__ float Ws[32][32];
    int t = threadIdx.x;
    long base = (long)blockIdx.x * 256;      // 8 tokens x 32
    int r = t >> 5, j = t & 31;
    long tok = (long)blockIdx.x * 8 + r;
    int h = j >> 3;

#pragma unroll
    for (int i = 0; i < 4; ++i) {
        int f = i * 256 + t;
        Ws[f >> 5][f & 31] = WO[f];
    }

    float L = 0.f, ctx = 0.f;
#pragma unroll
    for (int s2 = 0; s2 < NSEG; ++s2) {
        L   += pl[(size_t)s2 * NTOK * 4 + tok * 4 + h];
        ctx += pctx[((size_t)s2 * NTOK + tok) * 32 + j];
    }
    float sa = ctx / L;
    sa_out[base + t] = sa;
    sas[r][j] = sa;
    __syncthreads();

    float y = bO[j] + resid[base + t];
#pragma unroll
    for (int i = 0; i < 32; ++i) y = fmaf(sas[r][i], Ws[i][j], y);

    float sum = y;
#pragma unroll
    for (int o = 16; o >= 1; o >>= 1) sum += __shfl_xor(sum, o, 32);
    float mu = sum * (1.0f / 32.0f);
    float d  = y - mu;
    float sq = d * d;
#pragma unroll
    for (int o = 16; o >= 1; o >>= 1) sq += __shfl_xor(sq, o, 32);
    float var = sq * (1.0f / 32.0f);
    out0[base + t] = d * rsqrtf(var + LN_EPS);
}

// ---------------------------------------------------------------------------
extern "C" void kernel_launch(void* const* d_in, const int* in_sizes, int n_in,
                              void* d_out, int out_size, void* d_ws, size_t ws_size,
                              hipStream_t stream)
{
    const float* inQ = (const float*)d_in[0];
    const float* inK = (const float*)d_in[1];
    const float* inV = (const float*)d_in[2];
    const void*  mask = d_in[3];
    const float* WQ = (const float*)d_in[4];
    const float* bQ = (const float*)d_in[5];
    const float* WK = (const float*)d_in[6];
    const float* bK = (const float*)d_in[7];
    const float* WV = (const float*)d_in[8];
    const float* bV = (const float*)d_in[9];
    const float* WO = (const float*)d_in[10];
    const float* bO = (const float*)d_in[11];

    float* out0 = (float*)d_out;                    // layernorm output
    float* sa   = (float*)d_out + (long)NTOK * 32;  // self_attn output

    char* ws = (char*)d_ws;
    int*  flag = (int*)ws;
    unsigned short* Qh = (unsigned short*)(ws + 256);
    unsigned short* Ql = Qh + (long)NTOK * 32;
    unsigned short* Kh = Ql + (long)NTOK * 32;
    unsigned short* Kl = Kh + (long)NTOK * 32;
    unsigned short* Vt = Kl + (long)NTOK * 32;
    unsigned long long* pack = (unsigned long long*)(Vt + (long)NTOK * 32);
    float* pbase = (float*)(pack + (long)NTOK * (S_LEN / 64));

    size_t fixed  = 256 + 5ul * NTOK * 32 * 2 + (size_t)NTOK * (S_LEN / 64) * 8;
    size_t perseg = (size_t)NTOK * 36 * 4;
    int NS = 1;
    if      (fixed + 8 * perseg <= ws_size) NS = 8;
    else if (fixed + 4 * perseg <= ws_size) NS = 4;
    else if (fixed + 2 * perseg <= ws_size) NS = 2;

    float* pl   = pbase;
    float* pctx = pl + (long)NS * NTOK * 4;

    detect_mask_dtype<<<1, 64, 0, stream>>>((const unsigned char*)mask, flag);
    maskpack_kernel<<<NTOK / 4, 256, 0, stream>>>(mask, flag, pack);
    proj_kernel<<<dim3(NTOK / 8, 3), 256, 0, stream>>>(
        inQ, inK, inV, WQ, bQ, WK, bK, WV, bV, Qh, Ql, Kh, Kl, Vt);

    int agrid = B_SZ * NS * 16;
    int cgrid = NTOK / 8;
    switch (NS) {
    case 8:
        attn_kernel<8><<<agrid, 256, 0, stream>>>(Qh, Ql, Kh, Kl, Vt, pack, pl, pctx);
        combine_epilogue<8><<<cgrid, 256, 0, stream>>>(pl, pctx, WO, bO, inQ, sa, out0);
        break;
    case 4:
        attn_kernel<4><<<agrid, 256, 0, stream>>>(Qh, Ql, Kh, Kl, Vt, pack, pl, pctx);
        combine_epilogue<4><<<cgrid, 256, 0, stream>>>(pl, pctx, WO, bO, inQ, sa, out0);
        break;
    case 2:
        attn_kernel<2><<<agrid, 256, 0, stream>>>(Qh, Ql, Kh, Kl, Vt, pack, pl, pctx);
        combine_epilogue<2><<<cgrid, 256, 0, stream>>>(pl, pctx, WO, bO, inQ, sa, out0);
        break;
    default:
        attn_kernel<1><<<agrid, 256, 0, stream>>>(Qh, Ql, Kh, Kl, Vt, pack, pl, pctx);
        combine_epilogue<1><<<cgrid, 256, 0, stream>>>(pl, pctx, WO, bO, inQ, sa, out0);
        break;
    }
}

// Round 10
// 98.785 us; speedup vs baseline: 2.2680x; 1.0389x over previous
//
#include <hip/hip_runtime.h>
#include <math.h>

#define D_MODEL 32
#define S_LEN   2048
#define B_SZ    8
#define NTOK    (B_SZ * S_LEN)
#define LN_EPS  1e-5f
#define LOG2E   1.44269504088896340736f
#define QK_SCALE 0.35355339059327373f   /* 1/sqrt(8) */
#define MASKV   (-1.0e9f)               /* v_exp_f32(-1e9) == 0 */

typedef __attribute__((ext_vector_type(8)))  short    short8b;
typedef __attribute__((ext_vector_type(4)))  short    short4b;
typedef __attribute__((ext_vector_type(4)))  unsigned uint4v;
typedef __attribute__((ext_vector_type(16))) float    f32x16;

__device__ __forceinline__ unsigned short f2bf(float f) {   // RNE f32->bf16
    unsigned u = __builtin_bit_cast(unsigned, f);
    unsigned r = (u + 0x7FFFu + ((u >> 16) & 1u)) >> 16;
    return (unsigned short)r;
}
__device__ __forceinline__ float bf2f(unsigned short h) {
    return __builtin_bit_cast(float, (unsigned)h << 16);
}
__device__ __forceinline__ unsigned cvtpk_bf16(float lo, float hi) {
    unsigned r;
    asm("v_cvt_pk_bf16_f32 %0, %1, %2" : "=v"(r) : "v"(lo), "v"(hi));
    return r;
}

// ---------------------------------------------------------------------------
__global__ void detect_mask_dtype(const unsigned char* __restrict__ mb,
                                  int* __restrict__ flag) {
    int t = threadIdx.x;  // 64 lanes
    unsigned char b1 = mb[t * 4 + 1];
    unsigned char b2 = mb[t * 4 + 2];
    unsigned char b3 = mb[t * 4 + 3];
    int ok = ((b1 | b2 | b3) == 0);
    unsigned long long vote = __ballot(ok);
    if (t == 0) flag[0] = (vote == ~0ULL) ? 1 : 0;   // 1 => int32 layout
}

// ---------------------------------------------------------------------------
// Row-bitpack the mask (no transpose): pack[tok][w] bit j = mask[tok][64w+j]!=0.
__global__ __launch_bounds__(256) void maskpack_kernel(
    const void* __restrict__ mask, const int* __restrict__ flag_p,
    unsigned long long* __restrict__ pack)
{
    int tid = threadIdx.x;
    long row = (long)blockIdx.x * 4 + (tid >> 6);
    int lane = tid & 63;
    unsigned long long* prow = pack + row * (S_LEN / 64);
    if (flag_p[0]) {
        const int* mr = (const int*)mask + row * S_LEN;
#pragma unroll 4
        for (int it = 0; it < 32; ++it) {
            unsigned long long wv = __ballot(mr[it * 64 + lane] != 0);
            if (lane == 0) prow[it] = wv;
        }
    } else {
        const unsigned char* mr = (const unsigned char*)mask + row * S_LEN;
#pragma unroll 4
        for (int it = 0; it < 32; ++it) {
            unsigned long long wv = __ballot(mr[it * 64 + lane] != 0);
            if (lane == 0) prow[it] = wv;
        }
    }
}

// ---------------------------------------------------------------------------
// QKV projection. Q (pre-scaled by 1/sqrt(8)*log2e) and K are stored as
// SPLIT bf16 (hi = bf16(x), lo = bf16(x - hi)) so QK^T can be computed
// exactly with two MFMAs. V stored transposed per head, single bf16.
__global__ __launch_bounds__(256) void proj_kernel(
    const float* __restrict__ xQ, const float* __restrict__ xK,
    const float* __restrict__ xV,
    const float* __restrict__ WQ, const float* __restrict__ bQ,
    const float* __restrict__ WK, const float* __restrict__ bK,
    const float* __restrict__ WV, const float* __restrict__ bV,
    unsigned short* __restrict__ Qh, unsigned short* __restrict__ Ql,
    unsigned short* __restrict__ Kh, unsigned short* __restrict__ Kl,
    unsigned short* __restrict__ Vt)
{
    const float* x; const float* W; const float* bias; float scale;
    if (blockIdx.y == 0)      { x = xQ; W = WQ; bias = bQ; scale = QK_SCALE * LOG2E; }
    else if (blockIdx.y == 1) { x = xK; W = WK; bias = bK; scale = 1.0f; }
    else                      { x = xV; W = WV; bias = bV; scale = 1.0f; }

    __shared__ float xs[8][32];
    __shared__ float Ws[32][32];
    int t = threadIdx.x;
    long base = (long)blockIdx.x * 256;    // 8 rows x 32 cols
    xs[t >> 5][t & 31] = x[base + t];
#pragma unroll
    for (int i = 0; i < 4; ++i) {
        int f = i * 256 + t;
        Ws[f >> 5][f & 31] = W[f];
    }
    __syncthreads();
    int r = t >> 5, j = t & 31;
    float acc = bias[j];
#pragma unroll
    for (int i = 0; i < 32; ++i) acc = fmaf(xs[r][i], Ws[i][j], acc);
    acc *= scale;

    if (blockIdx.y == 0) {
        unsigned short hv = f2bf(acc);
        Qh[base + t] = hv;
        Ql[base + t] = f2bf(acc - bf2f(hv));
    } else if (blockIdx.y == 1) {
        unsigned short hv = f2bf(acc);
        Kh[base + t] = hv;
        Kl[base + t] = f2bf(acc - bf2f(hv));
    } else {
        long tok = (long)blockIdx.x * 8 + r;
        long b   = tok >> 11;
        long ti  = tok & (S_LEN - 1);
        int  h   = j >> 3, dv = j & 7;
        Vt[((b * 4 + h) * 8 + dv) * S_LEN + ti] = f2bf(acc);
    }
}

// ---------------------------------------------------------------------------
// MFMA flash attention (no-max, exp2 domain, split-K, EXACT QK via split-bf16).
// Wave = (b, seg, 32-q tile). HEAD LOOP OUTER (register-pressure fix): per
// head, one qhf/qlf/cpv live across the chunk loop. Per-output arithmetic is
// identical to the R8 kernel (loop interchange only).
template<int NSEG>
__global__ __launch_bounds__(256) void attn_kernel(
    const unsigned short* __restrict__ Qh, const unsigned short* __restrict__ Ql,
    const unsigned short* __restrict__ Kh, const unsigned short* __restrict__ Kl,
    const unsigned short* __restrict__ Vt,
    const unsigned long long* __restrict__ pack,
    float* __restrict__ pl, float* __restrict__ pctx)
{
    constexpr int SEGLEN = S_LEN / NSEG;
    constexpr int NCH    = SEGLEN / 32;
    const int nb    = NSEG * 16;            // blocks per batch (4 waves/block)
    int raw   = blockIdx.x;
    int total = B_SZ * nb;
    int cpx   = total >> 3;
    int cid   = (raw & 7) * cpx + (raw >> 3);   // XCD-contiguous
    int b     = cid / nb;
    int rem   = cid - b * nb;
    int seg   = rem >> 4;
    int qt    = (rem & 15) * 4 + (threadIdx.x >> 6);
    int lane  = threadIdx.x & 63;
    int q     = lane & 31;
    int half  = lane >> 5;
    int tok0  = qt * 32;
    long tokq = (long)b * S_LEN + tok0 + q;
    int k0    = seg * SEGLEN;

    f32x16 zero16;
#pragma unroll
    for (int i = 0; i < 16; ++i) zero16[i] = 0.0f;

    const unsigned long long* prow = pack + tokq * (S_LEN / 64);
    const unsigned short* Ksel = (half ? Kl : Kh) + (long)b * S_LEN * 32;

#pragma unroll 1
    for (int h = 0; h < 4; ++h) {
        short8b qhf = *(const short8b*)(Qh + tokq * 32 + h * 8);
        short8b qlf = *(const short8b*)(Ql + tokq * 32 + h * 8);
        f32x16 cpv = zero16;

        unsigned long long w = 0;
#pragma unroll 1
        for (int ch = 0; ch < NCH; ++ch) {
            int kc = k0 + ch * 32;
            if ((ch & 1) == 0) w = prow[kc >> 6];
            unsigned wh  = (ch & 1) ? (unsigned)(w >> 32) : (unsigned)w;
            unsigned wsh = wh >> (half * 4);
            float madd[16];
#pragma unroll
            for (int r = 0; r < 16; ++r) {
                const int cr = (r & 3) + 8 * (r >> 2);
                madd[r] = ((wsh >> cr) & 1u) ? MASKV : 0.0f;
            }

            // A rows m=lane&31 -> key kc+q; half0 supplies K_hi (k-slots 0-7),
            // half1 supplies K_lo (k-slots 8-15), both at d0-7 of head h.
            short8b kf = *(const short8b*)(Ksel + (long)(kc + q) * 32 + h * 8);
            f32x16 acc = __builtin_amdgcn_mfma_f32_32x32x16_bf16(kf, qhf, zero16, 0, 0, 0);
            acc = __builtin_amdgcn_mfma_f32_32x32x16_bf16(kf, qlf, acc, 0, 0, 0);

            unsigned pr[8];
#pragma unroll
            for (int j = 0; j < 8; ++j) {
                float p0 = __builtin_amdgcn_exp2f(acc[2 * j]     + madd[2 * j]);
                float p1 = __builtin_amdgcn_exp2f(acc[2 * j + 1] + madd[2 * j + 1]);
                pr[j] = cvtpk_bf16(p0, p1);
            }
            uint4v t1, t2;
            t1.x = pr[0]; t1.y = pr[1]; t1.z = pr[2]; t1.w = pr[3];
            t2.x = pr[4]; t2.y = pr[5]; t2.z = pr[6]; t2.w = pr[7];
            short8b pfa = __builtin_bit_cast(short8b, t1);
            short8b pfb = __builtin_bit_cast(short8b, t2);

            // V^T A-frags mirror P's (half, elem)->key mapping exactly, so the
            // shared k-slot permutation cancels regardless of HW slot order.
            short8b vf1, vf2;
            if (q < 8) {
                const unsigned short* vr =
                    Vt + (((long)b * 4 + h) * 8 + q) * S_LEN + kc + half * 4;
                short4b a0 = *(const short4b*)(vr);
                short4b a1 = *(const short4b*)(vr + 8);
                short4b a2 = *(const short4b*)(vr + 16);
                short4b a3 = *(const short4b*)(vr + 24);
                vf1 = __builtin_shufflevector(a0, a1, 0, 1, 2, 3, 4, 5, 6, 7);
                vf2 = __builtin_shufflevector(a2, a3, 0, 1, 2, 3, 4, 5, 6, 7);
            } else {
                short ov = (q == 8) ? (short)0x3F80 : (short)0;  // ones row -> l-sum
#pragma unroll
                for (int i = 0; i < 8; ++i) { vf1[i] = ov; vf2[i] = ov; }
            }
            cpv = __builtin_amdgcn_mfma_f32_32x32x16_bf16(vf1, pfa, cpv, 0, 0, 0);
            cpv = __builtin_amdgcn_mfma_f32_32x32x16_bf16(vf2, pfb, cpv, 0, 0, 0);
        }

        // C_PV: col=q; lower half regs0-3 = dv0-3, reg4 = row8 = l-sum;
        // upper half regs0-3 = dv4-7.
        float4 cv = make_float4(cpv[0], cpv[1], cpv[2], cpv[3]);
        *(float4*)(pctx + ((size_t)seg * NTOK + tokq) * 32 + h * 8 + half * 4) = cv;
        if (half == 0)
            pl[(size_t)seg * NTOK * 4 + tokq * 4 + h] = cpv[4];
    }
}

// ---------------------------------------------------------------------------
// Merge split-K partials (plain sums) -> sa; attn_out = sa@WO + bO + resid; LN.
template<int NSEG>
__global__ __launch_bounds__(256) void combine_epilogue(
    const float* __restrict__ pl, const float* __restrict__ pctx,
    const float* __restrict__ WO, const float* __restrict__ bO,
    const float* __restrict__ resid,
    float* __restrict__ sa_out, float* __restrict__ out0)
{
    __shared__ float sas[8][32];
    __shared__ float Ws[32][32];
    int t = threadIdx.x;
    long base = (long)blockIdx.x * 256;      // 8 tokens x 32
    int r = t >> 5, j = t & 31;
    long tok = (long)blockIdx.x * 8 + r;
    int h = j >> 3;

#pragma unroll
    for (int i = 0; i < 4; ++i) {
        int f = i * 256 + t;
        Ws[f >> 5][f & 31] = WO[f];
    }

    float L = 0.f, ctx = 0.f;
#pragma unroll
    for (int s2 = 0; s2 < NSEG; ++s2) {
        L   += pl[(size_t)s2 * NTOK * 4 + tok * 4 + h];
        ctx += pctx[((size_t)s2 * NTOK + tok) * 32 + j];
    }
    float sa = ctx / L;
    sa_out[base + t] = sa;
    sas[r][j] = sa;
    __syncthreads();

    float y = bO[j] + resid[base + t];
#pragma unroll
    for (int i = 0; i < 32; ++i) y = fmaf(sas[r][i], Ws[i][j], y);

    float sum = y;
#pragma unroll
    for (int o = 16; o >= 1; o >>= 1) sum += __shfl_xor(sum, o, 32);
    float mu = sum * (1.0f / 32.0f);
    float d  = y - mu;
    float sq = d * d;
#pragma unroll
    for (int o = 16; o >= 1; o >>= 1) sq += __shfl_xor(sq, o, 32);
    float var = sq * (1.0f / 32.0f);
    out0[base + t] = d * rsqrtf(var + LN_EPS);
}

// ---------------------------------------------------------------------------
extern "C" void kernel_launch(void* const* d_in, const int* in_sizes, int n_in,
                              void* d_out, int out_size, void* d_ws, size_t ws_size,
                              hipStream_t stream)
{
    const float* inQ = (const float*)d_in[0];
    const float* inK = (const float*)d_in[1];
    const float* inV = (const float*)d_in[2];
    const void*  mask = d_in[3];
    const float* WQ = (const float*)d_in[4];
    const float* bQ = (const float*)d_in[5];
    const float* WK = (const float*)d_in[6];
    const float* bK = (const float*)d_in[7];
    const float* WV = (const float*)d_in[8];
    const float* bV = (const float*)d_in[9];
    const float* WO = (const float*)d_in[10];
    const float* bO = (const float*)d_in[11];

    float* out0 = (float*)d_out;                    // layernorm output
    float* sa   = (float*)d_out + (long)NTOK * 32;  // self_attn output

    char* ws = (char*)d_ws;
    int*  flag = (int*)ws;
    unsigned short* Qh = (unsigned short*)(ws + 256);
    unsigned short* Ql = Qh + (long)NTOK * 32;
    unsigned short* Kh = Ql + (long)NTOK * 32;
    unsigned short* Kl = Kh + (long)NTOK * 32;
    unsigned short* Vt = Kl + (long)NTOK * 32;
    unsigned long long* pack = (unsigned long long*)(Vt + (long)NTOK * 32);
    float* pbase = (float*)(pack + (long)NTOK * (S_LEN / 64));

    size_t fixed  = 256 + 5ul * NTOK * 32 * 2 + (size_t)NTOK * (S_LEN / 64) * 8;
    size_t perseg = (size_t)NTOK * 36 * 4;
    int NS = 1;
    if      (fixed + 8 * perseg <= ws_size) NS = 8;
    else if (fixed + 4 * perseg <= ws_size) NS = 4;
    else if (fixed + 2 * perseg <= ws_size) NS = 2;

    float* pl   = pbase;
    float* pctx = pl + (long)NS * NTOK * 4;

    detect_mask_dtype<<<1, 64, 0, stream>>>((const unsigned char*)mask, flag);
    maskpack_kernel<<<NTOK / 4, 256, 0, stream>>>(mask, flag, pack);
    proj_kernel<<<dim3(NTOK / 8, 3), 256, 0, stream>>>(
        inQ, inK, inV, WQ, bQ, WK, bK, WV, bV, Qh, Ql, Kh, Kl, Vt);

    int agrid = B_SZ * NS * 16;
    int cgrid = NTOK / 8;
    switch (NS) {
    case 8:
        attn_kernel<8><<<agrid, 256, 0, stream>>>(Qh, Ql, Kh, Kl, Vt, pack, pl, pctx);
        combine_epilogue<8><<<cgrid, 256, 0, stream>>>(pl, pctx, WO, bO, inQ, sa, out0);
        break;
    case 4:
        attn_kernel<4><<<agrid, 256, 0, stream>>>(Qh, Ql, Kh, Kl, Vt, pack, pl, pctx);
        combine_epilogue<4><<<cgrid, 256, 0, stream>>>(pl, pctx, WO, bO, inQ, sa, out0);
        break;
    case 2:
        attn_kernel<2><<<agrid, 256, 0, stream>>>(Qh, Ql, Kh, Kl, Vt, pack, pl, pctx);
        combine_epilogue<2><<<cgrid, 256, 0, stream>>>(pl, pctx, WO, bO, inQ, sa, out0);
        break;
    default:
        attn_kernel<1><<<agrid, 256, 0, stream>>>(Qh, Ql, Kh, Kl, Vt, pack, pl, pctx);
        combine_epilogue<1><<<cgrid, 256, 0, stream>>>(pl, pctx, WO, bO, inQ, sa, out0);
        break;
    }
}